// Round 2
// baseline (3540.545 us; speedup 1.0000x reference)
//
#include <hip/hip_runtime.h>
#include <stdint.h>

#define N_TOK 8192
#define DIN   768
#define DSAE  16384
#define T_POS 4
#define K_SEL 32
#define EQCAP 64

// ---------------------------------------------------------------------------
// Kernel A: m[d] = mean over T of b_dec[t][d]   (768 outputs)
// ---------------------------------------------------------------------------
__global__ void mean_bdec_kernel(const float* __restrict__ b_dec,
                                 float* __restrict__ m) {
    int d = blockIdx.x * blockDim.x + threadIdx.x;
    if (d < DIN) {
        float s = 0.f;
#pragma unroll
        for (int t = 0; t < T_POS; ++t) s += b_dec[t * DIN + d];
        m[d] = s * (1.0f / T_POS);
    }
}

// ---------------------------------------------------------------------------
// Kernel B: bias2[j] = b_enc[j] - sum_d m[d] * W_enc[d][j]   (16384 outputs)
// (x - m) @ W + b_enc == x @ W + bias2
// ---------------------------------------------------------------------------
__global__ void bias2_kernel(const float* __restrict__ W_enc,
                             const float* __restrict__ b_enc,
                             const float* __restrict__ m,
                             float* __restrict__ bias2) {
    int j = blockIdx.x * blockDim.x + threadIdx.x;
    float s = b_enc[j];
    for (int d = 0; d < DIN; ++d) {
        s = fmaf(-m[d], W_enc[(size_t)d * DSAE + j], s);
    }
    bias2[j] = s;
}

// ---------------------------------------------------------------------------
// Kernel C: pre = x @ W_enc + bias2   (8192 x 16384, K=768), f32 SGEMM.
// BM=BN=128, BK=8, 256 threads, 8x8 microtile with split-halves mapping
// (cols tx*4 and tx*4+64; rows ty*4 and ty*4+64) -> LDS b128 reads are
// 2-way-per-bank (free) instead of 4-way.
// Writes directly into the z region of d_out.
// ---------------------------------------------------------------------------
#define BM 128
#define BN 128
#define BK 8

__launch_bounds__(256)
__global__ void encode_gemm_kernel(const float* __restrict__ x,
                                   const float* __restrict__ W_enc,
                                   const float* __restrict__ bias2,
                                   float* __restrict__ pre) {
    __shared__ __align__(16) float As[BK][BM];  // As[k][i] (A transposed)
    __shared__ __align__(16) float Bs[BK][BN];  // Bs[k][j]

    const int tid  = threadIdx.x;
    const int bx   = blockIdx.x;          // 0..127  (DSAE/BN)
    const int by   = blockIdx.y;          // 0..63   (N_TOK/BM)
    const int row0 = by * BM;
    const int col0 = bx * BN;

    const int tx  = tid & 15;
    const int ty  = tid >> 4;
    const int tx4 = tx * 4;
    const int ty4 = ty * 4;

    // global->LDS load assignments
    const int ar  = tid >> 1;             // 0..127 : A row within tile
    const int ac  = (tid & 1) * 4;        // 0 or 4 : A col (k) within tile
    const int bkr = tid >> 5;             // 0..7   : B row (k) within tile
    const int bc  = (tid & 31) * 4;       // 0..124 : B col within tile

    const float* aptr = x + (size_t)(row0 + ar) * DIN + ac;
    const float* bptr = W_enc + (size_t)bkr * DSAE + col0 + bc;

    float acc[8][8];
#pragma unroll
    for (int i = 0; i < 8; ++i)
#pragma unroll
        for (int j = 0; j < 8; ++j) acc[i][j] = 0.f;

    // prefetch first tile
    float4 av = *(const float4*)(aptr);
    float4 bv = *(const float4*)(bptr);

    for (int k0 = 0; k0 < DIN; k0 += BK) {
        // stage current tile to LDS
        As[ac + 0][ar] = av.x;
        As[ac + 1][ar] = av.y;
        As[ac + 2][ar] = av.z;
        As[ac + 3][ar] = av.w;
        *(float4*)&Bs[bkr][bc] = bv;
        __syncthreads();

        // issue next-tile global loads early (hide latency under compute)
        if (k0 + BK < DIN) {
            av = *(const float4*)(aptr + (k0 + BK));
            bv = *(const float4*)(bptr + (size_t)(k0 + BK) * DSAE);
        }

#pragma unroll
        for (int kk = 0; kk < BK; ++kk) {
            const float4 a0 = *(const float4*)&As[kk][ty4];
            const float4 a1 = *(const float4*)&As[kk][ty4 + 64];
            const float4 b0 = *(const float4*)&Bs[kk][tx4];
            const float4 b1 = *(const float4*)&Bs[kk][tx4 + 64];
            float a[8] = {a0.x, a0.y, a0.z, a0.w, a1.x, a1.y, a1.z, a1.w};
            float b[8] = {b0.x, b0.y, b0.z, b0.w, b1.x, b1.y, b1.z, b1.w};
#pragma unroll
            for (int i = 0; i < 8; ++i)
#pragma unroll
                for (int j = 0; j < 8; ++j)
                    acc[i][j] = fmaf(a[i], b[j], acc[i][j]);
        }
        __syncthreads();
    }

    // epilogue: + bias2, store
    const float4 bb0 = *(const float4*)(bias2 + col0 + tx4);
    const float4 bb1 = *(const float4*)(bias2 + col0 + tx4 + 64);
#pragma unroll
    for (int i = 0; i < 8; ++i) {
        const int rr = row0 + ((i < 4) ? (ty4 + i) : (64 + ty4 + (i - 4)));
        float* dst = pre + (size_t)rr * DSAE + col0;
        float4 o0, o1;
        o0.x = acc[i][0] + bb0.x; o0.y = acc[i][1] + bb0.y;
        o0.z = acc[i][2] + bb0.z; o0.w = acc[i][3] + bb0.w;
        o1.x = acc[i][4] + bb1.x; o1.y = acc[i][5] + bb1.y;
        o1.z = acc[i][6] + bb1.z; o1.w = acc[i][7] + bb1.w;
        *(float4*)(dst + tx4)      = o0;
        *(float4*)(dst + tx4 + 64) = o1;
    }
}

// ---------------------------------------------------------------------------
// Kernel D: per-row exact top-32 (radix select on sortable-u32 keys,
// lowest-index tie-break to match lax.top_k), rewrite z row (zeros + scatter),
// fused sparse decode x_hat = sum val * W_dec[-1][idx,:] + b_dec[-1].
// One block (256 threads) per row. Row is re-read from global each radix pass
// (stays L2-resident, avoids >64KB static LDS).
// ---------------------------------------------------------------------------
__device__ __forceinline__ uint32_t f2key(uint32_t b) {
    return (b & 0x80000000u) ? ~b : (b | 0x80000000u);
}

__launch_bounds__(256)
__global__ void topk_decode_kernel(float* __restrict__ z,          // N_TOK x DSAE (holds pre on entry)
                                   const float* __restrict__ W_dec,
                                   const float* __restrict__ b_dec,
                                   float* __restrict__ x_hat) {
    __shared__ uint32_t hist[256];
    __shared__ uint32_t scan[256];
    __shared__ uint32_t sh_prefix;
    __shared__ int      sh_r;
    __shared__ int      nsel, neq;
    __shared__ int      sel_idx[K_SEL];
    __shared__ float    sel_val[K_SEL];
    __shared__ int      eqlist[EQCAP];

    const int row = blockIdx.x;
    const int tid = threadIdx.x;
    float* zrow = z + (size_t)row * DSAE;

    if (tid == 0) { nsel = 0; neq = 0; }

    // ---- radix select: find exact key of the 32nd largest ----
    uint32_t prefix = 0u, prefmask = 0u;
    int r = K_SEL;
    for (int round = 0; round < 4; ++round) {
        const int shift = 24 - round * 8;
        hist[tid] = 0u;
        __syncthreads();
        for (int t = tid; t < DSAE; t += 256) {
            uint32_t kv = f2key(__float_as_uint(zrow[t]));
            if ((kv & prefmask) == prefix)
                atomicAdd(&hist[(kv >> shift) & 255u], 1u);
        }
        __syncthreads();
        // parallel inclusive suffix sum over 256 bins
        scan[tid] = hist[tid];
        __syncthreads();
        for (int off = 1; off < 256; off <<= 1) {
            uint32_t add = (tid + off < 256) ? scan[tid + off] : 0u;
            __syncthreads();
            scan[tid] += add;
            __syncthreads();
        }
        uint32_t sfx   = scan[tid];                       // count with digit >= tid
        uint32_t above = (tid < 255) ? scan[tid + 1] : 0u; // count with digit >  tid
        if (sfx >= (uint32_t)r && above < (uint32_t)r) {  // exactly one tid matches
            sh_prefix = prefix | ((uint32_t)tid << shift);
            sh_r      = r - (int)above;
        }
        __syncthreads();
        prefix = sh_prefix;
        r      = sh_r;
        prefmask |= (0xFFu << shift);
        __syncthreads();
    }
    const uint32_t vstar = prefix;   // exact key of the r-th largest among ==group

    // ---- collect: strictly greater -> selected; equal -> candidate list ----
    for (int t = tid; t < DSAE; t += 256) {
        uint32_t b  = __float_as_uint(zrow[t]);
        uint32_t kv = f2key(b);
        if (kv > vstar) {
            int p = atomicAdd(&nsel, 1);
            sel_idx[p] = t;
            sel_val[p] = __uint_as_float(b);
        } else if (kv == vstar) {
            int p = atomicAdd(&neq, 1);
            if (p < EQCAP) eqlist[p] = t;
        }
    }
    __syncthreads();

    // ---- among equals take the r lowest indices (lax.top_k tie-break) ----
    if (tid == 0) {
        uint32_t vb = (vstar & 0x80000000u) ? (vstar & 0x7FFFFFFFu) : ~vstar;
        float fv = __uint_as_float(vb);
        int need = r;
        if (neq <= EQCAP) {
            for (int s = 0; s < need; ++s) {
                int mi = 0x7FFFFFFF, mj = -1;
                for (int q = 0; q < neq; ++q)
                    if (eqlist[q] < mi) { mi = eqlist[q]; mj = q; }
                sel_idx[nsel] = mi; sel_val[nsel] = fv; ++nsel;
                eqlist[mj] = 0x7FFFFFFF;
            }
        } else {  // pathological duplicate count: serial scan in index order
            int got = 0;
            for (int t = 0; t < DSAE && got < need; ++t) {
                uint32_t kv = f2key(__float_as_uint(zrow[t]));
                if (kv == vstar) { sel_idx[nsel] = t; sel_val[nsel] = fv; ++nsel; ++got; }
            }
        }
    }
    __syncthreads();

    // ---- rewrite z row: zeros everywhere, then scatter the 32 values ----
    float4 z4; z4.x = 0.f; z4.y = 0.f; z4.z = 0.f; z4.w = 0.f;
    float4* zrow4 = (float4*)zrow;
    for (int t = tid; t < DSAE / 4; t += 256) zrow4[t] = z4;
    __syncthreads();                         // order zero-writes before scatter
    if (tid < K_SEL) zrow[sel_idx[tid]] = sel_val[tid];

    // ---- fused sparse decode ----
    const float* Wd = W_dec + (size_t)(T_POS - 1) * DSAE * DIN;
    const float* bd = b_dec + (T_POS - 1) * DIN;
    float a0 = bd[tid];
    float a1 = bd[tid + 256];
    float a2 = bd[tid + 512];
#pragma unroll 8
    for (int s = 0; s < K_SEL; ++s) {
        const float* wr = Wd + (size_t)sel_idx[s] * DIN;
        const float  v  = sel_val[s];
        a0 = fmaf(v, wr[tid],       a0);
        a1 = fmaf(v, wr[tid + 256], a1);
        a2 = fmaf(v, wr[tid + 512], a2);
    }
    float* xr = x_hat + (size_t)row * DIN;
    xr[tid]       = a0;
    xr[tid + 256] = a1;
    xr[tid + 512] = a2;
}

// ---------------------------------------------------------------------------
extern "C" void kernel_launch(void* const* d_in, const int* in_sizes, int n_in,
                              void* d_out, int out_size, void* d_ws, size_t ws_size,
                              hipStream_t stream) {
    const float* x     = (const float*)d_in[0];
    const float* W_enc = (const float*)d_in[1];
    const float* b_enc = (const float*)d_in[2];
    const float* W_dec = (const float*)d_in[3];
    const float* b_dec = (const float*)d_in[4];
    // d_in[5] = k (==32, fixed by problem shape)

    float* x_hat = (float*)d_out;                       // N_TOK * DIN
    float* z     = x_hat + (size_t)N_TOK * DIN;         // N_TOK * DSAE

    float* m     = (float*)d_ws;                        // [DIN]
    float* bias2 = m + DIN;                             // [DSAE]

    mean_bdec_kernel<<<(DIN + 255) / 256, 256, 0, stream>>>(b_dec, m);
    bias2_kernel<<<DSAE / 256, 256, 0, stream>>>(W_enc, b_enc, m, bias2);

    dim3 g2(DSAE / BN, N_TOK / BM);
    encode_gemm_kernel<<<g2, 256, 0, stream>>>(x, W_enc, bias2, z);

    topk_decode_kernel<<<N_TOK, 256, 0, stream>>>(z, W_dec, b_dec, x_hat);
}